// Round 1
// baseline (950.554 us; speedup 1.0000x reference)
//
#include <hip/hip_runtime.h>
#include <hip/hip_bf16.h>

#define D 64

// ---------------- degree / norm ----------------

__global__ __launch_bounds__(256) void deg_init(float* deg, int N) {
    int i = blockIdx.x * 256 + threadIdx.x;
    if (i < N) deg[i] = 1.0f;  // self loop
}

__global__ __launch_bounds__(256) void deg_count(const int* __restrict__ dst, float* deg, int E) {
    int i = blockIdx.x * 256 + threadIdx.x;
    if (i < E) atomicAdd(&deg[dst[i]], 1.0f);
}

__global__ __launch_bounds__(256) void make_dinv(float* deg, int N) {
    int i = blockIdx.x * 256 + threadIdx.x;
    if (i < N) deg[i] = rsqrtf(deg[i]);  // in place: deg -> dinv
}

// ---------------- GEMM + row scale:  hn[r] = (X[r] @ W) * dinv[r]; acc[r] = hn[r] ----------------
// 32 rows per block, 4 waves, each wave computes 8 rows; lane = output column.
__global__ __launch_bounds__(256) void gemm_scale(
    const float* __restrict__ X, const float* __restrict__ W,
    const float* __restrict__ dinv, float* __restrict__ hn,
    float* __restrict__ acc, int N)
{
    __shared__ float sW[D * D];    // 16 KB
    __shared__ float sX[32 * D];   // 8 KB
    int tid = threadIdx.x;
    int rowBase = blockIdx.x * 32;

    for (int i = tid; i < D * D; i += 256) sW[i] = W[i];
    for (int i = tid; i < 32 * D; i += 256) {
        int r = rowBase + (i >> 6);
        sX[i] = (r < N) ? X[r * D + (i & 63)] : 0.0f;
    }
    __syncthreads();

    int wave = tid >> 6, lane = tid & 63;
    float accv[8];
#pragma unroll
    for (int r = 0; r < 8; ++r) accv[r] = 0.0f;

    int xoff = (wave * 8) * D;
#pragma unroll 8
    for (int k = 0; k < D; ++k) {
        float wv = sW[k * D + lane];          // 2-way bank alias: free
#pragma unroll
        for (int r = 0; r < 8; ++r)
            accv[r] += sX[xoff + r * D + k] * wv;  // wave-uniform broadcast
    }

#pragma unroll
    for (int r = 0; r < 8; ++r) {
        int row = rowBase + wave * 8 + r;
        if (row < N) {
            float v = accv[r] * dinv[row];
            hn[row * D + lane]  = v;
            acc[row * D + lane] = v;   // self-loop init of accumulator
        }
    }
}

// ---------------- edge scatter: acc[dst] += hn[src]  (one wave per edge, lane = column) ----------------
__global__ __launch_bounds__(256) void scatter_edges(
    const int* __restrict__ src, const int* __restrict__ dst,
    const float* __restrict__ hn, float* __restrict__ acc, int E)
{
    int wid  = (int)((blockIdx.x * 256 + threadIdx.x) >> 6);
    int lane = threadIdx.x & 63;
    if (wid < E) {
        int s = src[wid];
        int d = dst[wid];
        float v = hn[s * D + lane];
        atomicAdd(&acc[d * D + lane], v);
    }
}

// ---------------- epilogue: out = relu(acc * dinv[row] + b) ----------------
__global__ __launch_bounds__(256) void finish(
    const float* __restrict__ acc, const float* __restrict__ dinv,
    const float* __restrict__ b, float* __restrict__ out, int total)
{
    int idx = blockIdx.x * 256 + threadIdx.x;
    if (idx < total) {
        int row = idx >> 6, c = idx & 63;
        float v = acc[idx] * dinv[row] + b[c];
        out[idx] = v > 0.0f ? v : 0.0f;
    }
}

extern "C" void kernel_launch(void* const* d_in, const int* in_sizes, int n_in,
                              void* d_out, int out_size, void* d_ws, size_t ws_size,
                              hipStream_t stream) {
    const float* x   = (const float*)d_in[0];
    const int*   ei  = (const int*)d_in[1];   // [2, E] int32
    const float* W1  = (const float*)d_in[2];
    const float* b1  = (const float*)d_in[3];
    const float* W2  = (const float*)d_in[4];
    const float* b2  = (const float*)d_in[5];

    int N = in_sizes[0] / D;
    int E = in_sizes[1] / 2;
    const int* src = ei;
    const int* dst = ei + E;

    // workspace layout
    float* dinv = (float*)d_ws;                              // N floats
    float* hn   = (float*)((char*)d_ws + (1 << 20));         // N*D floats (25.6 MB)
    float* outF = (float*)d_out;                             // doubles as scatter accumulator

    int nb_N  = (N + 255) / 256;
    int nb_E  = (E + 255) / 256;
    int nb_G  = (N + 31) / 32;
    int nb_W  = (E + 3) / 4;           // 4 edge-waves per 256-block
    int total = N * D;
    int nb_F  = (total + 255) / 256;

    // degrees -> dinv (shared by both layers)
    deg_init<<<nb_N, 256, 0, stream>>>(dinv, N);
    deg_count<<<nb_E, 256, 0, stream>>>(dst, dinv, E);
    make_dinv<<<nb_N, 256, 0, stream>>>(dinv, N);

    // ---- layer 1 ----
    gemm_scale<<<nb_G, 256, 0, stream>>>(x, W1, dinv, hn, outF, N);
    scatter_edges<<<nb_W, 256, 0, stream>>>(src, dst, hn, outF, E);
    finish<<<nb_F, 256, 0, stream>>>(outF, dinv, b1, hn, total);   // h1 -> hn

    // ---- layer 2 ----
    gemm_scale<<<nb_G, 256, 0, stream>>>(hn, W2, dinv, hn, outF, N);  // in-place on hn
    scatter_edges<<<nb_W, 256, 0, stream>>>(src, dst, hn, outF, E);
    finish<<<nb_F, 256, 0, stream>>>(outF, dinv, b2, outF, total);    // in-place on d_out
}

// Round 2
// 544.431 us; speedup vs baseline: 1.7460x; 1.7460x over previous
//
#include <hip/hip_runtime.h>
#include <hip/hip_bf16.h>

#define D 64

// ================= degree / norm =================

__global__ __launch_bounds__(256) void zero_deg(int* deg, int N) {
    int i = blockIdx.x * 256 + threadIdx.x;
    if (i < N) deg[i] = 0;
}

__global__ __launch_bounds__(256) void deg_count(const int* __restrict__ dst, int* deg, int E) {
    int i = blockIdx.x * 256 + threadIdx.x;
    if (i < E) atomicAdd(&deg[dst[i]], 1);
}

__global__ __launch_bounds__(256) void make_dinv(const int* __restrict__ deg, float* dinv, int N) {
    int i = blockIdx.x * 256 + threadIdx.x;
    if (i < N) dinv[i] = rsqrtf((float)(deg[i] + 1));  // +1 self loop
}

// ================= CSR build: 2-level exclusive scan + fill =================

__global__ __launch_bounds__(256) void block_sums(const int* __restrict__ deg, int* __restrict__ partials, int N) {
    __shared__ int lds[256];
    int tid = threadIdx.x, gid = blockIdx.x * 256 + tid;
    lds[tid] = (gid < N) ? deg[gid] : 0;
    __syncthreads();
    for (int s = 128; s > 0; s >>= 1) {
        if (tid < s) lds[tid] += lds[tid + s];
        __syncthreads();
    }
    if (tid == 0) partials[blockIdx.x] = lds[0];
}

// single 64-lane wave scans partials in-place -> exclusive
__global__ void scan_partials(int* __restrict__ p, int nb) {
    int lane = threadIdx.x;
    int carry = 0;
    for (int base = 0; base < nb; base += 64) {
        int i = base + lane;
        int v = (i < nb) ? p[i] : 0;
        int orig = v;
        for (int d = 1; d < 64; d <<= 1) {
            int t = __shfl_up(v, d, 64);
            if (lane >= d) v += t;
        }
        int tot = __shfl(v, 63, 64);
        int excl = v - orig + carry;
        if (i < nb) p[i] = excl;
        carry += tot;
    }
}

__global__ __launch_bounds__(256) void scan_block(
    const int* __restrict__ deg, const int* __restrict__ blockOfs,
    int* __restrict__ ofs, int* __restrict__ cursor, int N, int E)
{
    __shared__ int lds[256];
    int tid = threadIdx.x, gid = blockIdx.x * 256 + tid;
    int v = (gid < N) ? deg[gid] : 0;
    lds[tid] = v;
    __syncthreads();
    for (int d = 1; d < 256; d <<= 1) {
        int t = (tid >= d) ? lds[tid - d] : 0;
        __syncthreads();
        lds[tid] += t;
        __syncthreads();
    }
    int excl = lds[tid] - v + blockOfs[blockIdx.x];
    if (gid < N) { ofs[gid] = excl; cursor[gid] = excl; }
    if (gid == 0) ofs[N] = E;
}

__global__ __launch_bounds__(256) void fill_csr(
    const int* __restrict__ src, const int* __restrict__ dst,
    int* __restrict__ cursor, int* __restrict__ csr, int E)
{
    int i = blockIdx.x * 256 + threadIdx.x;
    if (i < E) {
        int pos = atomicAdd(&cursor[dst[i]], 1);
        csr[pos] = src[i];
    }
}

// ================= GEMM + row scale: hn[r] = (X[r] @ W) * dinv[r] =================
// 32 rows/block, 4 waves, 8 rows/wave, lane = output column.
__global__ __launch_bounds__(256) void gemm_scale(
    const float* __restrict__ X, const float* __restrict__ W,
    const float* __restrict__ dinv, float* __restrict__ hn, int N)
{
    __shared__ float sW[D * D];    // 16 KB
    __shared__ float sX[32 * D];   // 8 KB
    int tid = threadIdx.x;
    int rowBase = blockIdx.x * 32;

    for (int i = tid; i < D * D; i += 256) sW[i] = W[i];
    for (int i = tid; i < 32 * D; i += 256) {
        int r = rowBase + (i >> 6);
        sX[i] = (r < N) ? X[r * D + (i & 63)] : 0.0f;
    }
    __syncthreads();

    int wave = tid >> 6, lane = tid & 63;
    float accv[8];
#pragma unroll
    for (int r = 0; r < 8; ++r) accv[r] = 0.0f;

    int xoff = (wave * 8) * D;
#pragma unroll 8
    for (int k = 0; k < D; ++k) {
        float wv = sW[k * D + lane];
#pragma unroll
        for (int r = 0; r < 8; ++r)
            accv[r] += sX[xoff + r * D + k] * wv;
    }

#pragma unroll
    for (int r = 0; r < 8; ++r) {
        int row = rowBase + wave * 8 + r;
        if (row < N) hn[row * D + lane] = accv[r] * dinv[row];
    }
}

// ================= pull aggregation + fused epilogue =================
// one wave per node; acc = hn[node] (self loop) + sum over neighbors hn[s];
// out = relu(acc * dinv[node] + b)
__global__ __launch_bounds__(256) void aggregate_relu(
    const int* __restrict__ ofs, const int* __restrict__ csr,
    const float* __restrict__ hn, const float* __restrict__ dinv,
    const float* __restrict__ bias, float* __restrict__ out, int N)
{
    int wid  = (int)((blockIdx.x * 256 + threadIdx.x) >> 6);
    int lane = threadIdx.x & 63;
    if (wid >= N) return;

    int s0 = ofs[wid], s1 = ofs[wid + 1];
    float acc = hn[wid * D + lane];           // self loop (norm folded into hn & dinv)

    for (int j = s0; j < s1; j += 64) {
        int idx = 0;
        if (j + lane < s1) idx = csr[j + lane];
        int cnt = min(64, s1 - j);
        for (int t = 0; t < cnt; ++t) {
            int s = __shfl(idx, t, 64);
            acc += hn[s * D + lane];
        }
    }

    float v = acc * dinv[wid] + bias[lane];
    out[wid * D + lane] = fmaxf(v, 0.0f);
}

// ================= launcher =================

extern "C" void kernel_launch(void* const* d_in, const int* in_sizes, int n_in,
                              void* d_out, int out_size, void* d_ws, size_t ws_size,
                              hipStream_t stream) {
    const float* x   = (const float*)d_in[0];
    const int*   ei  = (const int*)d_in[1];   // [2, E] int32
    const float* W1  = (const float*)d_in[2];
    const float* b1  = (const float*)d_in[3];
    const float* W2  = (const float*)d_in[4];
    const float* b2  = (const float*)d_in[5];

    int N = in_sizes[0] / D;
    int E = in_sizes[1] / 2;
    const int* src = ei;
    const int* dst = ei + E;

    // workspace layout (byte offsets)
    char* ws = (char*)d_ws;
    int*   deg      = (int*)  (ws + 0);                 // N
    float* dinv     = (float*)(ws + (1 << 19));         // N        @0.5MB
    int*   ofs      = (int*)  (ws + (2 << 19));         // N+1      @1.0MB
    int*   cursor   = (int*)  (ws + (3 << 19));         // N        @1.5MB
    int*   partials = (int*)  (ws + (4 << 19));         // ~391     @2.0MB
    int*   csr      = (int*)  (ws + (5 << 19));         // E        @2.5MB
    float* hn       = (float*)(ws + (24 << 19));        // N*D      @12MB
    float* outF     = (float*)d_out;

    int nb_N = (N + 255) / 256;
    int nb_E = (E + 255) / 256;
    int nb_G = (N + 31) / 32;
    int nb_A = (N + 3) / 4;      // 4 node-waves per block

    // ---- shared preprocessing: degrees, dinv, CSR ----
    zero_deg     <<<nb_N, 256, 0, stream>>>(deg, N);
    deg_count    <<<nb_E, 256, 0, stream>>>(dst, deg, E);
    make_dinv    <<<nb_N, 256, 0, stream>>>(deg, dinv, N);
    block_sums   <<<nb_N, 256, 0, stream>>>(deg, partials, N);
    scan_partials<<<1,    64,  0, stream>>>(partials, nb_N);
    scan_block   <<<nb_N, 256, 0, stream>>>(deg, partials, ofs, cursor, N, E);
    fill_csr     <<<nb_E, 256, 0, stream>>>(src, dst, cursor, csr, E);

    // ---- layer 1 ----
    gemm_scale    <<<nb_G, 256, 0, stream>>>(x, W1, dinv, hn, N);
    aggregate_relu<<<nb_A, 256, 0, stream>>>(ofs, csr, hn, dinv, b1, outF, N);

    // ---- layer 2 ----
    gemm_scale    <<<nb_G, 256, 0, stream>>>(outF, W2, dinv, hn, N);
    aggregate_relu<<<nb_A, 256, 0, stream>>>(ofs, csr, hn, dinv, b2, outF, N);
}

// Round 3
// 362.937 us; speedup vs baseline: 2.6191x; 1.5001x over previous
//
#include <hip/hip_runtime.h>
#include <hip/hip_bf16.h>

#define D 64

// =============== K2: fused deg_count(+rank) and GEMM1 (hn = X @ W, unscaled) ===============
// blocks [0, nbD): edge histogram, saving per-edge rank (atomicAdd return) as u8
// blocks [nbD, nbD+nbG): 32-rows-per-block GEMM
__global__ __launch_bounds__(256) void deg_and_gemm(
    const int* __restrict__ dst, int* __restrict__ deg, unsigned char* __restrict__ rank, int E, int nbD,
    const float* __restrict__ X, const float* __restrict__ W, float* __restrict__ hn, int N)
{
    __shared__ float sW[D * D];    // 16 KB
    __shared__ float sX[32 * D];   // 8 KB
    int tid = threadIdx.x;

    if ((int)blockIdx.x < nbD) {
        int stride = nbD * 256;
        for (int i = blockIdx.x * 256 + tid; i < E; i += stride) {
            int d = dst[i];
            rank[i] = (unsigned char)atomicAdd(&deg[d], 1);
        }
        return;
    }

    int rowBase = ((int)blockIdx.x - nbD) * 32;

    // stage W (1024 float4) and X rows (512 float4)
    for (int i = tid; i < 1024; i += 256)
        ((float4*)sW)[i] = ((const float4*)W)[i];
    for (int i = tid; i < 512; i += 256) {
        int r = rowBase + (i >> 4);
        float4 v = make_float4(0.f, 0.f, 0.f, 0.f);
        if (r < N) v = ((const float4*)X)[rowBase * 16 + i];
        ((float4*)sX)[i] = v;
    }
    __syncthreads();

    int wave = tid >> 6, lane = tid & 63;
    float accv[8];
#pragma unroll
    for (int r = 0; r < 8; ++r) accv[r] = 0.0f;

    int xoff = (wave * 8) * D;
#pragma unroll 8
    for (int k = 0; k < D; ++k) {
        float wv = sW[k * D + lane];
#pragma unroll
        for (int r = 0; r < 8; ++r)
            accv[r] += sX[xoff + r * D + k] * wv;
    }
#pragma unroll
    for (int r = 0; r < 8; ++r) {
        int row = rowBase + wave * 8 + r;
        if (row < N) hn[row * D + lane] = accv[r];
    }
}

// plain GEMM (layer 2): hn = X @ W
__global__ __launch_bounds__(256) void gemm(
    const float* __restrict__ X, const float* __restrict__ W,
    float* __restrict__ hn, int N)
{
    __shared__ float sW[D * D];
    __shared__ float sX[32 * D];
    int tid = threadIdx.x;
    int rowBase = blockIdx.x * 32;

    for (int i = tid; i < 1024; i += 256)
        ((float4*)sW)[i] = ((const float4*)W)[i];
    for (int i = tid; i < 512; i += 256) {
        int r = rowBase + (i >> 4);
        float4 v = make_float4(0.f, 0.f, 0.f, 0.f);
        if (r < N) v = ((const float4*)X)[rowBase * 16 + i];
        ((float4*)sX)[i] = v;
    }
    __syncthreads();

    int wave = tid >> 6, lane = tid & 63;
    float accv[8];
#pragma unroll
    for (int r = 0; r < 8; ++r) accv[r] = 0.0f;

    int xoff = (wave * 8) * D;
#pragma unroll 8
    for (int k = 0; k < D; ++k) {
        float wv = sW[k * D + lane];
#pragma unroll
        for (int r = 0; r < 8; ++r)
            accv[r] += sX[xoff + r * D + k] * wv;
    }
#pragma unroll
    for (int r = 0; r < 8; ++r) {
        int row = rowBase + wave * 8 + r;
        if (row < N) hn[row * D + lane] = accv[r];
    }
}

// =============== K3: dinv + atomic block-scan for CSR range assignment ===============
// ofs[i] gets a disjoint range of length deg[i] (order nondeterministic — fine)
__global__ __launch_bounds__(256) void dinv_scan(
    const int* __restrict__ deg, float* __restrict__ dinv,
    int* __restrict__ ofs, int* __restrict__ ctr, int N)
{
    __shared__ int lds[256];
    __shared__ int base;
    int tid = threadIdx.x, gid = blockIdx.x * 256 + tid;
    int v = (gid < N) ? deg[gid] : 0;
    if (gid < N) dinv[gid] = rsqrtf((float)(v + 1));   // +1 self loop
    lds[tid] = v;
    __syncthreads();
    for (int d2 = 1; d2 < 256; d2 <<= 1) {
        int t = (tid >= d2) ? lds[tid - d2] : 0;
        __syncthreads();
        lds[tid] += t;
        __syncthreads();
    }
    if (tid == 255) base = atomicAdd(ctr, lds[255]);
    __syncthreads();
    if (gid < N) ofs[gid] = base + lds[tid] - v;       // exclusive
}

// =============== K4: atomic-free CSR fill ===============
__global__ __launch_bounds__(256) void fill_csr(
    const int* __restrict__ src, const int* __restrict__ dst,
    const unsigned char* __restrict__ rank, const int* __restrict__ ofs,
    int* __restrict__ csr, int E)
{
    int i = blockIdx.x * 256 + threadIdx.x;
    if (i < E) {
        int d = dst[i];
        csr[ofs[d] + (int)rank[i]] = src[i];
    }
}

// =============== K5: pull aggregation + epilogue ===============
// one wave per node, 4 groups of 16 lanes; group g handles neighbors g, g+4, g+8, ...
// acc += hn[s] * dinv[s]; out = relu(acc_total * dinv[node] + b)
__global__ __launch_bounds__(256) void aggregate_relu(
    const int* __restrict__ ofs, const int* __restrict__ deg,
    const int* __restrict__ csr, const float* __restrict__ hn,
    const float* __restrict__ dinv, const float* __restrict__ bias,
    float* __restrict__ out, int N)
{
    int wid  = (int)((blockIdx.x * 256 + threadIdx.x) >> 6);
    int lane = threadIdx.x & 63;
    if (wid >= N) return;
    int grp = lane >> 4, sub = lane & 15;

    int s0 = ofs[wid];
    int s1 = s0 + deg[wid];

    const float4* hn4 = (const float4*)hn;
    float ax = 0.f, ay = 0.f, az = 0.f, aw = 0.f;

    if (grp == 0) {                       // self loop
        float ds = dinv[wid];
        float4 v = hn4[wid * 16 + sub];
        ax = v.x * ds; ay = v.y * ds; az = v.z * ds; aw = v.w * ds;
    }

    for (int p = s0 + grp; p < s1; p += 4) {
        int s = csr[p];                   // 4 consecutive ints per wave-instr
        float ds = dinv[s];
        float4 v = hn4[s * 16 + sub];     // 4 x 256B segments per wave-instr
        ax += v.x * ds; ay += v.y * ds; az += v.z * ds; aw += v.w * ds;
    }

    // cross-group reduce (lanes sub, sub+16, sub+32, sub+48 hold same cols)
    ax += __shfl_xor(ax, 16, 64); ay += __shfl_xor(ay, 16, 64);
    az += __shfl_xor(az, 16, 64); aw += __shfl_xor(aw, 16, 64);
    ax += __shfl_xor(ax, 32, 64); ay += __shfl_xor(ay, 32, 64);
    az += __shfl_xor(az, 32, 64); aw += __shfl_xor(aw, 32, 64);

    if (grp == 0) {
        float dw = dinv[wid];
        float4 b = ((const float4*)bias)[sub];
        float4 o;
        o.x = fmaxf(ax * dw + b.x, 0.f);
        o.y = fmaxf(ay * dw + b.y, 0.f);
        o.z = fmaxf(az * dw + b.z, 0.f);
        o.w = fmaxf(aw * dw + b.w, 0.f);
        ((float4*)out)[wid * 16 + sub] = o;
    }
}

// =============== launcher ===============

extern "C" void kernel_launch(void* const* d_in, const int* in_sizes, int n_in,
                              void* d_out, int out_size, void* d_ws, size_t ws_size,
                              hipStream_t stream) {
    const float* x   = (const float*)d_in[0];
    const int*   ei  = (const int*)d_in[1];   // [2, E] int32
    const float* W1  = (const float*)d_in[2];
    const float* b1  = (const float*)d_in[3];
    const float* W2  = (const float*)d_in[4];
    const float* b2  = (const float*)d_in[5];

    int N = in_sizes[0] / D;
    int E = in_sizes[1] / 2;
    const int* src = ei;
    const int* dst = ei + E;

    // workspace layout (byte offsets; total < 36.2 MB)
    char* ws = (char*)d_ws;
    int*           deg  = (int*)  (ws + 0);             // N ints   (400 KB)
    int*           ctr  = (int*)  (ws + 0x00080000);    // 1 int
    float*         dinv = (float*)(ws + 0x00100000);    // N floats
    int*           ofs  = (int*)  (ws + 0x00180000);    // N ints
    unsigned char* rank = (unsigned char*)(ws + 0x00200000);  // E bytes (1.6 MB)
    int*           csr  = (int*)  (ws + 0x003A0000);    // E ints   (6.4 MB)
    float*         hn   = (float*)(ws + 0x00A80000);    // N*D floats (25.6 MB)
    float*         outF = (float*)d_out;

    int nb_N = (N + 255) / 256;
    int nb_E = (E + 255) / 256;
    int nb_G = (N + 31) / 32;
    int nb_A = (N + 3) / 4;
    int nbD  = 1024;                      // grid-stride edge blocks in fused kernel

    // zero deg + ctr (deg is first, ctr right after the deg region)
    hipMemsetAsync(deg, 0, (size_t)0x00080000 + 4, stream);

    // deg/rank histogram overlapped with layer-1 GEMM
    deg_and_gemm<<<nbD + nb_G, 256, 0, stream>>>(dst, deg, rank, E, nbD, x, W1, hn, N);
    // dinv + CSR range assignment (atomic block scan)
    dinv_scan<<<nb_N, 256, 0, stream>>>(deg, dinv, ofs, ctr, N);
    // atomic-free CSR fill
    fill_csr<<<nb_E, 256, 0, stream>>>(src, dst, rank, ofs, csr, E);

    // layer 1 aggregate -> h1 (in d_out temporarily)
    aggregate_relu<<<nb_A, 256, 0, stream>>>(ofs, deg, csr, hn, dinv, b1, outF, N);
    // layer 2 GEMM: hn = h1 @ W2
    gemm<<<nb_G, 256, 0, stream>>>(outF, W2, hn, N);
    // layer 2 aggregate -> out
    aggregate_relu<<<nb_A, 256, 0, stream>>>(ofs, deg, csr, hn, dinv, b2, outF, N);
}